// Round 1
// baseline (11152.337 us; speedup 1.0000x reference)
//
#include <hip/hip_runtime.h>
#include <hip/hip_cooperative_groups.h>

namespace cg_ns = cooperative_groups;

#define NT 256
#define NB 1024
#define MAXIT 100
#define RTOL_F 1e-5f

__device__ __forceinline__ float gload(const float* p) {
    return __hip_atomic_load(p, __ATOMIC_RELAXED, __HIP_MEMORY_SCOPE_AGENT);
}

// Inclusive scan of one int per thread across the block (NT=256), via LDS.
__device__ __forceinline__ int block_incl_scan(int v, int* smi) {
    const int t = threadIdx.x;
    smi[t] = v;
    __syncthreads();
#pragma unroll
    for (int off = 1; off < NT; off <<= 1) {
        int add = (t >= off) ? smi[t - off] : 0;
        __syncthreads();
        v += add;
        smi[t] = v;
        __syncthreads();
    }
    return v;
}

// Block-reduce float and atomicAdd the block total into *dst.
__device__ __forceinline__ void block_reduce_add(float v, float* dst, float* smf) {
#pragma unroll
    for (int o = 32; o > 0; o >>= 1) v += __shfl_down(v, o);
    const int t = threadIdx.x;
    __syncthreads();  // protect smf reuse
    if ((t & 63) == 0) smf[t >> 6] = v;
    __syncthreads();
    if (t == 0) atomicAdd(dst, smf[0] + smf[1] + smf[2] + smf[3]);
}

__global__ void __launch_bounds__(NT, 4)
cg_solver_kernel(const float* __restrict__ values,
                 const float4* __restrict__ bvec,
                 const int* __restrict__ rowi,
                 const int* __restrict__ coli,
                 float4* __restrict__ x,      // = d_out
                 float4* __restrict__ r,
                 float4* __restrict__ p,
                 float4* __restrict__ q,
                 int* __restrict__ row_ptr,   // n+1
                 int* __restrict__ counts,    // n (scratch)
                 int* __restrict__ bsum,      // NB
                 float* __restrict__ scal,    // 256: [0..100]=rho_k, [128..227]=pq_k
                 int2* __restrict__ csr,      // nnz interleaved {col, val_bits}
                 int n, int nnz)
{
    cg_ns::grid_group grid = cg_ns::this_grid();
    const int t = threadIdx.x;
    const int tid = blockIdx.x * NT + t;
    const int nth = gridDim.x * NT;
    __shared__ int smi[NT];
    __shared__ float smf[NT / 64];

    // ---- Phase A: zero counts + scalar slots (ws is poisoned every call) ----
    for (int i = tid; i < n; i += nth) counts[i] = 0;
    if (tid < 256) scal[tid] = 0.f;
    grid.sync();

    // ---- Phase B: row histogram + init r=p=b, x=0, bnorm2 ----
    for (int e = tid; e < nnz; e += nth) atomicAdd(&counts[rowi[e]], 1);
    float acc = 0.f;
    for (int i = tid; i < n; i += nth) {
        float4 bv = bvec[i];
        r[i] = bv;
        p[i] = bv;
        x[i] = make_float4(0.f, 0.f, 0.f, 0.f);
        acc += bv.x * bv.x + bv.y * bv.y + bv.z * bv.z + bv.w * bv.w;
    }
    block_reduce_add(acc, &scal[0], smf);
    grid.sync();

    // ---- Phase C: per-block exclusive scan of counts (1 row/thread; n == nth) ----
    {
        int c = (tid < n) ? counts[tid] : 0;
        int incl = block_incl_scan(c, smi);
        if (tid < n) row_ptr[tid] = incl - c;  // local exclusive
        if (t == NT - 1) bsum[blockIdx.x] = incl;
    }
    grid.sync();

    // ---- Phase D: block 0 scans the NB block totals (4 per thread) ----
    if (blockIdx.x == 0) {
        const int nb = gridDim.x;
        const int base = t * 4;
        int g0 = (base + 0 < nb) ? bsum[base + 0] : 0;
        int g1 = (base + 1 < nb) ? bsum[base + 1] : 0;
        int g2 = (base + 2 < nb) ? bsum[base + 2] : 0;
        int g3 = (base + 3 < nb) ? bsum[base + 3] : 0;
        int local = g0 + g1 + g2 + g3;
        int incl = block_incl_scan(local, smi);
        int excl = incl - local;
        if (base + 0 < nb) bsum[base + 0] = excl;
        if (base + 1 < nb) bsum[base + 1] = excl + g0;
        if (base + 2 < nb) bsum[base + 2] = excl + g0 + g1;
        if (base + 3 < nb) bsum[base + 3] = excl + g0 + g1 + g2;
    }
    grid.sync();

    // ---- Phase E: finalize row_ptr; counts becomes running scatter offset ----
    if (tid < n) {
        int rp = row_ptr[tid] + bsum[blockIdx.x];
        row_ptr[tid] = rp;
        counts[tid] = rp;
    }
    if (tid == 0) row_ptr[n] = nnz;
    grid.sync();

    // ---- Phase F: scatter COO -> CSR (interleaved col/val) ----
    for (int e = tid; e < nnz; e += nth) {
        int rr = rowi[e];
        int pos = atomicAdd(&counts[rr], 1);
        csr[pos] = make_int2(coli[e], __float_as_int(values[e]));
    }
    grid.sync();

    // ---- CG loop (reference semantics: while sqrt(rho) > RTOL*||b|| && k<100) ----
    const float bnorm2 = gload(&scal[0]);
    const float tol2 = RTOL_F * RTOL_F * bnorm2;
    float rho = bnorm2;
    int k = 0;
    while (rho > tol2 && k < MAXIT) {
        // q = A p, fused with pdot = p.q
        float pdot = 0.f;
        if (tid < n) {
            int s = row_ptr[tid], e2 = row_ptr[tid + 1];
            float4 a4 = make_float4(0.f, 0.f, 0.f, 0.f);
            for (int j = s; j < e2; ++j) {
                int2 cv = csr[j];
                float v = __int_as_float(cv.y);
                float4 pv = p[cv.x];
                a4.x = fmaf(v, pv.x, a4.x);
                a4.y = fmaf(v, pv.y, a4.y);
                a4.z = fmaf(v, pv.z, a4.z);
                a4.w = fmaf(v, pv.w, a4.w);
            }
            q[tid] = a4;
            float4 pi = p[tid];
            pdot = a4.x * pi.x + a4.y * pi.y + a4.z * pi.z + a4.w * pi.w;
        }
        block_reduce_add(pdot, &scal[128 + k], smf);
        grid.sync();

        float alpha = rho / gload(&scal[128 + k]);
        float rr2 = 0.f;
        if (tid < n) {
            float4 pi = p[tid], qi = q[tid], ri = r[tid], xi = x[tid];
            xi.x = fmaf(alpha, pi.x, xi.x);
            xi.y = fmaf(alpha, pi.y, xi.y);
            xi.z = fmaf(alpha, pi.z, xi.z);
            xi.w = fmaf(alpha, pi.w, xi.w);
            ri.x = fmaf(-alpha, qi.x, ri.x);
            ri.y = fmaf(-alpha, qi.y, ri.y);
            ri.z = fmaf(-alpha, qi.z, ri.z);
            ri.w = fmaf(-alpha, qi.w, ri.w);
            x[tid] = xi;
            r[tid] = ri;
            rr2 = ri.x * ri.x + ri.y * ri.y + ri.z * ri.z + ri.w * ri.w;
        }
        block_reduce_add(rr2, &scal[k + 1], smf);
        grid.sync();

        float rho_new = gload(&scal[k + 1]);
        float beta = rho_new / rho;
        if (tid < n) {
            float4 ri = r[tid], pi = p[tid];
            pi.x = fmaf(beta, pi.x, ri.x);
            pi.y = fmaf(beta, pi.y, ri.y);
            pi.z = fmaf(beta, pi.z, ri.z);
            pi.w = fmaf(beta, pi.w, ri.w);
            p[tid] = pi;
        }
        grid.sync();

        rho = rho_new;
        ++k;
    }
    // x already lives in d_out; nothing else to write.
}

extern "C" void kernel_launch(void* const* d_in, const int* in_sizes, int n_in,
                              void* d_out, int out_size, void* d_ws, size_t ws_size,
                              hipStream_t stream) {
    const float* values = (const float*)d_in[0];
    const float4* bvec  = (const float4*)d_in[1];
    const int* rowi     = (const int*)d_in[2];
    const int* coli     = (const int*)d_in[3];
    const int nnz = in_sizes[0];
    const int n   = in_sizes[1] / 4;  // F = 4

    char* ws = (char*)d_ws;
    size_t off = 0;
    auto alloc = [&](size_t bytes) -> void* {
        off = (off + 255) & ~(size_t)255;
        void* pp = ws + off;
        off += bytes;
        return pp;
    };
    float4* r     = (float4*)alloc((size_t)n * 16);
    float4* p     = (float4*)alloc((size_t)n * 16);
    float4* q     = (float4*)alloc((size_t)n * 16);
    int* row_ptr  = (int*)alloc((size_t)(n + 1) * 4);
    int* counts   = (int*)alloc((size_t)n * 4);
    int* bsum     = (int*)alloc((size_t)NB * 4);
    float* scal   = (float*)alloc(256 * 4);
    int2* csr     = (int2*)alloc((size_t)nnz * 8);
    float4* x     = (float4*)d_out;

    int n_ = n, nnz_ = nnz;
    void* args[] = {
        (void*)&values, (void*)&bvec, (void*)&rowi, (void*)&coli,
        (void*)&x, (void*)&r, (void*)&p, (void*)&q,
        (void*)&row_ptr, (void*)&counts, (void*)&bsum, (void*)&scal,
        (void*)&csr, (void*)&n_, (void*)&nnz_
    };
    hipLaunchCooperativeKernel((void*)cg_solver_kernel, dim3(NB), dim3(NT),
                               args, 0, stream);
}

// Round 3
// 9825.787 us; speedup vs baseline: 1.1350x; 1.1350x over previous
//
#include <hip/hip_runtime.h>
#include <hip/hip_cooperative_groups.h>

namespace cg_ns = cooperative_groups;

#define NT 256
#define NB 1024           // 1024*256 = 262144 threads = n; 4 blocks/CU (proven to launch)
#define MAXIT 100
#define RTOL_F 1e-5f
// SELL-64x1: slice = 64 rows = one wave, 1 lane per row.
// entry j of row -> sell[soff[slice] + j*64 + (row & 63)]

__device__ __forceinline__ float gload(const float* p) {
    return __hip_atomic_load(p, __ATOMIC_RELAXED, __HIP_MEMORY_SCOPE_AGENT);
}

// Inclusive scan of one int per thread across the block (NT), via LDS.
__device__ __forceinline__ int block_incl_scan(int v, int* smi) {
    const int t = threadIdx.x;
    smi[t] = v;
    __syncthreads();
#pragma unroll
    for (int off = 1; off < NT; off <<= 1) {
        int add = (t >= off) ? smi[t - off] : 0;
        __syncthreads();
        v += add;
        smi[t] = v;
        __syncthreads();
    }
    return v;
}

// Block-reduce float and atomicAdd the block total into *dst.
__device__ __forceinline__ void block_reduce_add(float v, float* dst, float* smf) {
#pragma unroll
    for (int o = 32; o > 0; o >>= 1) v += __shfl_down(v, o);
    const int t = threadIdx.x;
    __syncthreads();  // protect smf reuse across calls
    if ((t & 63) == 0) smf[t >> 6] = v;
    __syncthreads();
    if (t == 0) atomicAdd(dst, smf[0] + smf[1] + smf[2] + smf[3]);
}

__global__ void __launch_bounds__(NT, 4)
cg_solver_kernel(const float* __restrict__ values,
                 const float4* __restrict__ bvec,
                 const int* __restrict__ rowi,
                 const int* __restrict__ coli,
                 float4* __restrict__ x,      // = d_out
                 float4* __restrict__ r,
                 float4* __restrict__ p,
                 float4* __restrict__ q,
                 int* __restrict__ counts,    // n: row lengths
                 int* __restrict__ ridx,      // n: scatter cursors
                 int* __restrict__ jarr,      // nslice: padded slot-count per slice
                 int* __restrict__ soff,      // nslice+1: slice offsets (entries)
                 float* __restrict__ scal,    // 256: [0..100]=rho_k, [128..228]=pq_k
                 long long* __restrict__ sell,// SELL entries: low32=col, high32=val bits
                 int n, int nnz, int nslice)
{
    cg_ns::grid_group grid = cg_ns::this_grid();
    const int t = threadIdx.x;
    const int tid = blockIdx.x * NT + t;
    const int nth = gridDim.x * NT;          // == n
    __shared__ int smi[NT];
    __shared__ float smf[NT / 64];

    // ---- Phase A: zero counters + scalar slots (ws poisoned every call) ----
    for (int i = tid; i < n; i += nth) { counts[i] = 0; ridx[i] = 0; }
    if (tid < 256) scal[tid] = 0.f;
    grid.sync();

    // ---- Phase B: row histogram + init r=p=b, x=0, bnorm2 ----
    for (int e = tid; e < nnz; e += nth) atomicAdd(&counts[rowi[e]], 1);
    float acc = 0.f;
    if (tid < n) {
        float4 bv = bvec[tid];
        r[tid] = bv;
        p[tid] = bv;
        x[tid] = make_float4(0.f, 0.f, 0.f, 0.f);
        acc = bv.x * bv.x + bv.y * bv.y + bv.z * bv.z + bv.w * bv.w;
    }
    block_reduce_add(acc, &scal[0], smf);
    grid.sync();

    // ---- Phase C: per-slice padded slot count J (multiple of 4) ----
    for (int s = tid; s < nslice; s += nth) {
        const int rb = s << 6;
        int m = 0;
#pragma unroll 4
        for (int i = 0; i < 64; ++i) m = max(m, counts[rb + i]);
        jarr[s] = (m + 3) & ~3;     // pad for unroll-4
    }
    grid.sync();

    // ---- Phase D: block 0 scans slice sizes -> soff ----
    if (blockIdx.x == 0) {
        const int spt = (nslice + NT - 1) / NT;   // slices per thread
        const int base = t * spt;
        int local = 0;
        for (int i = 0; i < spt; ++i) {
            int s = base + i;
            if (s < nslice) local += 64 * jarr[s];
        }
        int incl = block_incl_scan(local, smi);
        int run = incl - local;
        for (int i = 0; i < spt; ++i) {
            int s = base + i;
            if (s < nslice) { soff[s] = run; run += 64 * jarr[s]; }
        }
        if (t == NT - 1) soff[nslice] = incl;     // total padded entries
    }
    grid.sync();

    // ---- Phase E: zero-fill SELL (col=0, val=0 padding is harmless) ----
    {
        const int total = soff[nslice];
        for (int i = tid; i < total; i += nth) sell[i] = 0LL;
    }
    grid.sync();

    // ---- Phase F: scatter COO -> SELL ----
    for (int e = tid; e < nnz; e += nth) {
        const int rr = rowi[e];
        const int i = atomicAdd(&ridx[rr], 1);
        const int pos = soff[rr >> 6] + (i << 6) + (rr & 63);
        sell[pos] = ((long long)__float_as_int(values[e]) << 32) | (unsigned int)coli[e];
    }
    grid.sync();

    // ---- CG loop ----
    const int wid = tid >> 6;          // wave id == slice id
    const int lane = t & 63;
    const float bnorm2 = gload(&scal[0]);
    const float tol2 = RTOL_F * RTOL_F * bnorm2;
    float rho = bnorm2;
    int k = 0;
    while (rho > tol2 && k < MAXIT) {
        // --- q = A p (SELL-64x1, coalesced, unroll-4), fused pdot = p.q ---
        float4 a4 = make_float4(0.f, 0.f, 0.f, 0.f);
        {
            const long long* bp = sell + soff[wid] + lane;
            const int J = jarr[wid];
            for (int j = 0; j < J; j += 4) {
                const long long e0 = __builtin_nontemporal_load(bp + (j + 0) * 64);
                const long long e1 = __builtin_nontemporal_load(bp + (j + 1) * 64);
                const long long e2 = __builtin_nontemporal_load(bp + (j + 2) * 64);
                const long long e3 = __builtin_nontemporal_load(bp + (j + 3) * 64);
                const float4 p0 = p[(int)(e0 & 0xffffffff)];
                const float4 p1 = p[(int)(e1 & 0xffffffff)];
                const float4 p2 = p[(int)(e2 & 0xffffffff)];
                const float4 p3 = p[(int)(e3 & 0xffffffff)];
                const float v0 = __int_as_float((int)(e0 >> 32));
                const float v1 = __int_as_float((int)(e1 >> 32));
                const float v2 = __int_as_float((int)(e2 >> 32));
                const float v3 = __int_as_float((int)(e3 >> 32));
                a4.x = fmaf(v0, p0.x, a4.x); a4.y = fmaf(v0, p0.y, a4.y);
                a4.z = fmaf(v0, p0.z, a4.z); a4.w = fmaf(v0, p0.w, a4.w);
                a4.x = fmaf(v1, p1.x, a4.x); a4.y = fmaf(v1, p1.y, a4.y);
                a4.z = fmaf(v1, p1.z, a4.z); a4.w = fmaf(v1, p1.w, a4.w);
                a4.x = fmaf(v2, p2.x, a4.x); a4.y = fmaf(v2, p2.y, a4.y);
                a4.z = fmaf(v2, p2.z, a4.z); a4.w = fmaf(v2, p2.w, a4.w);
                a4.x = fmaf(v3, p3.x, a4.x); a4.y = fmaf(v3, p3.y, a4.y);
                a4.z = fmaf(v3, p3.z, a4.z); a4.w = fmaf(v3, p3.w, a4.w);
            }
        }
        float pdot = 0.f;
        {
            q[tid] = a4;
            const float4 pi = p[tid];
            pdot = a4.x * pi.x + a4.y * pi.y + a4.z * pi.z + a4.w * pi.w;
        }
        block_reduce_add(pdot, &scal[128 + k], smf);
        grid.sync();

        // --- x += alpha p; r -= alpha q; rho_new = r.r ---
        const float alpha = rho / gload(&scal[128 + k]);
        float rr2 = 0.f;
        {
            const float4 pi = p[tid];
            const float4 qi = q[tid];
            float4 ri = r[tid];
            float4 xi = x[tid];
            xi.x = fmaf(alpha, pi.x, xi.x);
            xi.y = fmaf(alpha, pi.y, xi.y);
            xi.z = fmaf(alpha, pi.z, xi.z);
            xi.w = fmaf(alpha, pi.w, xi.w);
            ri.x = fmaf(-alpha, qi.x, ri.x);
            ri.y = fmaf(-alpha, qi.y, ri.y);
            ri.z = fmaf(-alpha, qi.z, ri.z);
            ri.w = fmaf(-alpha, qi.w, ri.w);
            x[tid] = xi;
            r[tid] = ri;
            rr2 = ri.x * ri.x + ri.y * ri.y + ri.z * ri.z + ri.w * ri.w;
        }
        block_reduce_add(rr2, &scal[k + 1], smf);
        grid.sync();

        // --- p = r + beta p ---
        const float rho_new = gload(&scal[k + 1]);
        const float beta = rho_new / rho;
        {
            const float4 ri = r[tid];
            float4 pi = p[tid];
            pi.x = fmaf(beta, pi.x, ri.x);
            pi.y = fmaf(beta, pi.y, ri.y);
            pi.z = fmaf(beta, pi.z, ri.z);
            pi.w = fmaf(beta, pi.w, ri.w);
            p[tid] = pi;
        }
        grid.sync();

        rho = rho_new;
        ++k;
    }
}

extern "C" void kernel_launch(void* const* d_in, const int* in_sizes, int n_in,
                              void* d_out, int out_size, void* d_ws, size_t ws_size,
                              hipStream_t stream) {
    const float* values = (const float*)d_in[0];
    const float4* bvec  = (const float4*)d_in[1];
    const int* rowi     = (const int*)d_in[2];
    const int* coli     = (const int*)d_in[3];
    const int nnz = in_sizes[0];
    const int n   = in_sizes[1] / 4;  // F = 4
    const int nslice = n / 64;        // 64 rows per wave-slice

    char* ws = (char*)d_ws;
    size_t off = 0;
    auto alloc = [&](size_t bytes) -> void* {
        off = (off + 255) & ~(size_t)255;
        void* pp = ws + off;
        off += bytes;
        return pp;
    };
    float4* r    = (float4*)alloc((size_t)n * 16);
    float4* p    = (float4*)alloc((size_t)n * 16);
    float4* q    = (float4*)alloc((size_t)n * 16);
    int* counts  = (int*)alloc((size_t)n * 4);
    int* ridx    = (int*)alloc((size_t)n * 4);
    int* jarr    = (int*)alloc((size_t)nslice * 4);
    int* soff    = (int*)alloc((size_t)(nslice + 1) * 4);
    float* scal  = (float*)alloc(256 * 4);
    // SELL gets the rest of the workspace (~60 MB needed for this problem).
    off = (off + 255) & ~(size_t)255;
    long long* sell = (long long*)(ws + off);
    float4* x = (float4*)d_out;

    int n_ = n, nnz_ = nnz, nslice_ = nslice;
    void* args[] = {
        (void*)&values, (void*)&bvec, (void*)&rowi, (void*)&coli,
        (void*)&x, (void*)&r, (void*)&p, (void*)&q,
        (void*)&counts, (void*)&ridx, (void*)&jarr, (void*)&soff,
        (void*)&scal, (void*)&sell, (void*)&n_, (void*)&nnz_, (void*)&nslice_
    };
    hipLaunchCooperativeKernel((void*)cg_solver_kernel, dim3(NB), dim3(NT),
                               args, 0, stream);
}